// Round 3
// baseline (8729.805 us; speedup 1.0000x reference)
//
#include <hip/hip_runtime.h>
#include <hip/hip_bf16.h>

// Video_multilevel_encoding — round 3: MFMA bf16 GEMMs (m97 structure: 128x128 tile,
// 4 waves x (4x4) 16x16x32 tiles, global_load_lds width-16 staging, 2-barrier K-loop).
// Legacy VALU GEMM retained as runtime-gated f32 fallback and for the tiny map GEMM.
// Carried facts: attention is dead (softmax over size-1 axis == 1); convs are NT-GEMMs
// + shift-add/max epilogue; inputs probed bf16 (round-2 PASS, absmax 4.9e-4).

#define T_SEQ 80

typedef __attribute__((ext_vector_type(8))) short short8;
typedef __attribute__((ext_vector_type(4))) float floatx4;

__device__ __forceinline__ float bf2f(unsigned short s) {
    union { unsigned int u; float f; } c; c.u = ((unsigned int)s) << 16; return c.f;
}
__device__ __forceinline__ unsigned short f2bf(float f) {
    union { float f; unsigned int u; } c; c.f = f;
    unsigned int u = c.u;
    u += 0x7fffu + ((u >> 16) & 1u);   // RNE
    return (unsigned short)(u >> 16);
}
__device__ __forceinline__ float ldsc(const void* p, long i, int f32m) {
    return f32m ? ((const float*)p)[i] : bf2f(((const unsigned short*)p)[i]);
}
__device__ __forceinline__ void ld8(const void* p, long i, int f32m, float* o) {
    if (f32m) {
        const float* q = (const float*)p + i;
        float4 a = *(const float4*)q, b = *(const float4*)(q + 4);
        o[0]=a.x; o[1]=a.y; o[2]=a.z; o[3]=a.w; o[4]=b.x; o[5]=b.y; o[6]=b.z; o[7]=b.w;
    } else {
        uint4 v = *(const uint4*)((const unsigned short*)p + i);
        o[0]=bf2f((unsigned short)(v.x & 0xffffu)); o[1]=bf2f((unsigned short)(v.x >> 16));
        o[2]=bf2f((unsigned short)(v.y & 0xffffu)); o[3]=bf2f((unsigned short)(v.y >> 16));
        o[4]=bf2f((unsigned short)(v.z & 0xffffu)); o[5]=bf2f((unsigned short)(v.z >> 16));
        o[6]=bf2f((unsigned short)(v.w & 0xffffu)); o[7]=bf2f((unsigned short)(v.w >> 16));
    }
}

// async global->LDS, 16B per lane; lds dest must be wave-uniform (HW: base + lane*16)
__device__ __forceinline__ void gld16(const unsigned short* g, unsigned short* lds_uniform) {
    __builtin_amdgcn_global_load_lds(
        (const __attribute__((address_space(1))) void*)g,
        (__attribute__((address_space(3))) void*)lds_uniform, 16, 0, 0);
}

// Probe: bf16 (flag=0) vs f32 (flag=1) storage of float tensors.
__global__ void k_probe(const unsigned short* __restrict__ v, int* __restrict__ flag) {
    int tid = threadIdx.x;  // 64
    int bad = 0;
    #pragma unroll
    for (int u = 0; u < 4; ++u) {
        float x = bf2f(v[tid * 4 + u]);
        float ax = fabsf(x);
        if (!(ax <= 64.f) || (ax != 0.f && ax < 9.094947e-13f)) bad++;
    }
    #pragma unroll
    for (int off = 32; off >= 1; off >>= 1) bad += __shfl_down(bad, off, 64);
    if (tid == 0) *flag = (bad >= 16) ? 1 : 0;
}

// ---------------------------------------------------------------------------
// MFMA bf16 NT-GEMM (bf16-mode only; early-exits if probed f32).
// C[m,n] = sum_k A[m,k]*B[n,k] (+bias). Same addressing scheme as legacy gemm_nt.
// 128x128 tile, BK=32, 256 thr (4 waves, each a 64x64 quadrant = 4x4 MFMA tiles).
// Requires M%128==0, N%128==0, K%32==0; A/B rows 16B-aligned (true for all call sites).
// ---------------------------------------------------------------------------
template<int OUTBF>
__global__ __launch_bounds__(256) void gemm_mfma(
    const unsigned short* __restrict__ A, long a_base, int a_rpb, long a_bstride, int a_rstride,
    const unsigned short* __restrict__ B1, const unsigned short* __restrict__ B2,
    int n_split, int b_mod, long b_sa, long b_sb,
    const unsigned short* __restrict__ bias1, const unsigned short* __restrict__ bias2, int has_bias,
    void* __restrict__ Cout, long out_dsplit, long ldc, int K,
    const int* __restrict__ dtf)
{
    if (*dtf) return;   // f32 inputs -> legacy path handles it
    __shared__ __align__(16) unsigned short As[128 * 32];
    __shared__ __align__(16) unsigned short Bs[128 * 32];
    const int tid = threadIdx.x;
    const int wave = tid >> 6, lane = tid & 63;
    const int m0 = blockIdx.y * 128, n0 = blockIdx.x * 128;

    // staging: 512 16B-chunks per tile (row-major [128][32] bf16), 2 chunks/thread
    const int c0 = wave * 64 + lane;          // q=0 chunk
    const int c1 = 256 + c0;                  // q=1 chunk
    unsigned short* ldsA0 = As + (wave * 64) * 8;          // wave-uniform
    unsigned short* ldsA1 = As + (256 + wave * 64) * 8;
    unsigned short* ldsB0 = Bs + (wave * 64) * 8;
    unsigned short* ldsB1 = Bs + (256 + wave * 64) * 8;

    const int rA0 = c0 >> 2, pA0 = c0 & 3, rA1 = c1 >> 2, pA1 = c1 & 3;
    const int am0 = m0 + rA0, am1 = m0 + rA1;
    const unsigned short* gA0 = A + a_base + (long)(am0 / a_rpb) * a_bstride + (long)(am0 % a_rpb) * a_rstride + pA0 * 8;
    const unsigned short* gA1 = A + a_base + (long)(am1 / a_rpb) * a_bstride + (long)(am1 % a_rpb) * a_rstride + pA1 * 8;

    const int bn0 = n0 + rA0, bn1 = n0 + rA1;
    const int bd0 = (bn0 >= n_split), bd1 = (bn1 >= n_split);
    const int br0 = bn0 - (bd0 ? n_split : 0), br1 = bn1 - (bd1 ? n_split : 0);
    const unsigned short* gB0 = (bd0 ? B2 : B1) + (long)(br0 % b_mod) * b_sa + (long)(br0 / b_mod) * b_sb + pA0 * 8;
    const unsigned short* gB1 = (bd1 ? B2 : B1) + (long)(br1 % b_mod) * b_sa + (long)(br1 / b_mod) * b_sb + pA1 * 8;

    const int frow = lane & 15, fq = lane >> 4;
    const int wm = (wave >> 1) * 64, wn = (wave & 1) * 64;

    floatx4 acc[4][4];
    #pragma unroll
    for (int i = 0; i < 4; ++i)
        #pragma unroll
        for (int j = 0; j < 4; ++j) acc[i][j] = (floatx4)0.f;

    for (int k0 = 0; k0 < K; k0 += 32) {
        gld16(gA0 + k0, ldsA0);
        gld16(gA1 + k0, ldsA1);
        gld16(gB0 + k0, ldsB0);
        gld16(gB1 + k0, ldsB1);
        __syncthreads();
        short8 af[4], bf[4];
        #pragma unroll
        for (int i = 0; i < 4; ++i) {
            af[i] = *(const short8*)&As[(wm + i * 16 + frow) * 32 + fq * 8];
            bf[i] = *(const short8*)&Bs[(wn + i * 16 + frow) * 32 + fq * 8];
        }
        #pragma unroll
        for (int mi = 0; mi < 4; ++mi)
            #pragma unroll
            for (int ni = 0; ni < 4; ++ni)
                acc[mi][ni] = __builtin_amdgcn_mfma_f32_16x16x32_bf16(af[mi], bf[ni], acc[mi][ni], 0, 0, 0);
        __syncthreads();
    }

    // C/D layout: col = lane&15, row = (lane>>4)*4 + r
    #pragma unroll
    for (int mi = 0; mi < 4; ++mi) {
        #pragma unroll
        for (int ni = 0; ni < 4; ++ni) {
            const int na = n0 + wn + ni * 16 + frow;
            const int dd = (na >= n_split);
            const int g  = na - (dd ? n_split : 0);
            float bv = has_bias ? bf2f((dd ? bias2 : bias1)[g]) : 0.f;
            #pragma unroll
            for (int r = 0; r < 4; ++r) {
                const long gm = m0 + wm + mi * 16 + fq * 4 + r;
                const float v = acc[mi][ni][r] + bv;
                const long cidx = (dd ? out_dsplit : 0) + gm * ldc + g;
                if (OUTBF) ((unsigned short*)Cout)[cidx] = f2bf(v);
                else       ((float*)Cout)[cidx] = v;
            }
        }
    }
}

// ---------------------------------------------------------------------------
// Legacy VALU NT-GEMM (dual-dtype). gate: 0=always run, 2=only if f32 inputs.
// ---------------------------------------------------------------------------
template<int AMODE, int OUTBF>
__global__ __launch_bounds__(256) void gemm_nt(
    const void* __restrict__ Av, long a_base, int a_rpb, long a_bstride, int a_rstride,
    const void* __restrict__ B1, const void* __restrict__ B2,
    int n_split, int b_mod, long b_sa, long b_sb,
    const void* __restrict__ bias1, const void* __restrict__ bias2, int has_bias,
    void* __restrict__ Cout, long out_dsplit, long ldc, int K,
    int gate, const int* __restrict__ dtf)
{
    const int f32m = *dtf;
    if (gate == 2 && !f32m) return;
    __shared__ float As[16][132];
    __shared__ float Bs[16][132];
    const int tid = threadIdx.x;
    const int m0 = blockIdx.y * 128, n0 = blockIdx.x * 128;

    const int srow = tid >> 1;
    const int k8   = (tid & 1) * 8;
    const int am   = m0 + srow;
    const long aoff = a_base + (long)(am / a_rpb) * a_bstride + (long)(am % a_rpb) * a_rstride + k8;
    const int bn = n0 + srow;
    const int bd = (bn >= n_split) ? 1 : 0;
    const int br = bn - (bd ? n_split : 0);
    const void* Bbase = bd ? B2 : B1;
    const long boff = (long)(br % b_mod) * b_sa + (long)(br / b_mod) * b_sb + k8;

    const int tx = tid & 15, ty = tid >> 4;
    float acc[8][8];
    #pragma unroll
    for (int i = 0; i < 8; ++i)
        #pragma unroll
        for (int j = 0; j < 8; ++j) acc[i][j] = 0.f;

    for (int k0 = 0; k0 < K; k0 += 16) {
        float ta[8], tb[8];
        if (AMODE == 0)      ld8(Av, aoff + k0, 1, ta);
        else if (AMODE == 1) ld8(Av, aoff + k0, 0, ta);
        else                 ld8(Av, aoff + k0, f32m, ta);
        ld8(Bbase, boff + k0, f32m, tb);
        #pragma unroll
        for (int i = 0; i < 8; ++i) As[k8 + i][srow] = ta[i];
        #pragma unroll
        for (int i = 0; i < 8; ++i) Bs[k8 + i][srow] = tb[i];
        __syncthreads();
        #pragma unroll
        for (int kk = 0; kk < 16; ++kk) {
            float a[8], b[8];
            *(float4*)&a[0] = *(const float4*)&As[kk][ty*8];
            *(float4*)&a[4] = *(const float4*)&As[kk][ty*8+4];
            *(float4*)&b[0] = *(const float4*)&Bs[kk][tx*8];
            *(float4*)&b[4] = *(const float4*)&Bs[kk][tx*8+4];
            #pragma unroll
            for (int i = 0; i < 8; ++i)
                #pragma unroll
                for (int j = 0; j < 8; ++j)
                    acc[i][j] += a[i]*b[j];
        }
        __syncthreads();
    }
    #pragma unroll
    for (int i = 0; i < 8; ++i) {
        const long m = m0 + ty*8 + i;
        #pragma unroll
        for (int j = 0; j < 8; ++j) {
            int na = n0 + tx*8 + j;
            int dd = (na >= n_split) ? 1 : 0;
            int g  = na - (dd ? n_split : 0);
            float v = acc[i][j];
            if (has_bias) v += ldsc(dd ? bias2 : bias1, g, f32m);
            long cidx = (dd ? out_dsplit : 0) + m*ldc + g;
            if (OUTBF) ((unsigned short*)Cout)[cidx] = f2bf(v);
            else       ((float*)Cout)[cidx] = v;
        }
    }
}

// Pre-transpose Whh -> Wt f32 [d][gate][k][j] (j contiguous), bhh -> f32.
__global__ __launch_bounds__(256) void k_prep(
    const void* __restrict__ Whh_f, const void* __restrict__ Whh_b,
    const void* __restrict__ bhh_f, const void* __restrict__ bhh_b,
    float* __restrict__ Wt, float* __restrict__ bhh32, const int* __restrict__ dtf)
{
    const int f32m = *dtf;
    int e = blockIdx.x * 256 + threadIdx.x;      // < 1572864
    int k  = e & 511;
    int j  = (e >> 9) & 511;
    int q  = e >> 18;                            // 0..5 = d*3+gate
    int d  = (q >= 3) ? 1 : 0;
    int g3 = q - d * 3;
    Wt[((long)q * 512 + k) * 512 + j] = ldsc(d ? Whh_b : Whh_f, (long)(g3 * 512 + j) * 512 + k, f32m);
    if (e < 3072) {
        int dd = (e >= 1536) ? 1 : 0;
        int g  = e - dd * 1536;
        bhh32[e] = ldsc(dd ? bhh_b : bhh_f, g, f32m);
    }
}

// One GRU step, both directions. pre: bf16 [d][b*80+t][1536]; Mp out: bf16 [b][88][1024].
__global__ __launch_bounds__(256) void k_gru_step(
    int t,
    const unsigned short* __restrict__ pre, const float* __restrict__ Wt,
    const float* __restrict__ bhh32,
    const float* __restrict__ h_prev, float* __restrict__ h_next,
    unsigned short* __restrict__ Mp)
{
    __shared__ float hs[16][513];
    const int tid = threadIdx.x;
    const int d  = blockIdx.z;
    const int b0 = blockIdx.y * 16;
    const int j0 = blockIdx.x * 32;
    #pragma unroll
    for (int u = 0; u < 32; ++u) {
        int e = u * 256 + tid;
        int bb = e >> 9, k = e & 511;
        hs[bb][k] = h_prev[(((long)d * 128 + b0 + bb) << 9) + k];
    }
    __syncthreads();
    const int jq = tid & 15, bg = tid >> 4;
    const int j = j0 + jq * 2;
    const int b = b0 + bg;
    const float* wr = Wt + (long)d * 786432 + j;
    const float* wz = wr + 262144;
    const float* wn = wz + 262144;
    float ar0=0.f, ar1=0.f, az0=0.f, az1=0.f, an0=0.f, an1=0.f;
    #pragma unroll 8
    for (int k = 0; k < 512; ++k) {
        float hv = hs[bg][k];
        float2 r2 = *(const float2*)(wr + (k << 9));
        float2 z2 = *(const float2*)(wz + (k << 9));
        float2 n2 = *(const float2*)(wn + (k << 9));
        ar0 += r2.x * hv; ar1 += r2.y * hv;
        az0 += z2.x * hv; az1 += z2.y * hv;
        an0 += n2.x * hv; an1 += n2.y * hv;
    }
    const int ti = d ? (T_SEQ - 1 - t) : t;
    const unsigned short* pb = pre + (long)d * 15728640 + ((long)b * T_SEQ + ti) * 1536 + j;
    const float* bh = bhh32 + d * 1536 + j;
    float* hn = h_next + (((long)d * 128 + b) << 9) + j;
    unsigned short* mp = Mp + (long)b * 90112 + (long)(4 + ti) * 1024 + d * 512 + j;
    #pragma unroll
    for (int u = 0; u < 2; ++u) {
        float gr = (u ? ar1 : ar0) + bh[u];
        float gz = (u ? az1 : az0) + bh[512 + u];
        float gn = (u ? an1 : an0) + bh[1024 + u];
        float r = 1.f / (1.f + expf(-(bf2f(pb[u]) + gr)));
        float z = 1.f / (1.f + expf(-(bf2f(pb[512 + u]) + gz)));
        float n = tanhf(bf2f(pb[1024 + u]) + r * gn);
        float hnew = (1.f - z) * n + z * hs[bg][j + u];
        hn[u] = hnew;
        mp[u] = f2bf(hnew);
    }
}

// Mask Mp in place and compute mean over valid steps.
__global__ __launch_bounds__(256) void k_mask_mean(
    unsigned short* __restrict__ Mp, const void* __restrict__ mask,
    const int* __restrict__ lengths, float* __restrict__ mean, const int* __restrict__ dtf)
{
    const int f32m = *dtf;
    const int b = blockIdx.y;
    const int c = blockIdx.x * 256 + threadIdx.x;
    float acc = 0.f;
    unsigned short* base = Mp + (long)b * 90112 + 4096 + c;
    for (int t = 0; t < T_SEQ; ++t) {
        float m = ldsc(mask, b * T_SEQ + t, f32m);
        float v = bf2f(base[t * 1024]) * m;
        base[t * 1024] = f2bf(v);
        acc += v;
    }
    mean[b * 1024 + c] = acc / (float)lengths[b];
}

// Conv epilogue over bf16 D: c[b,kf,t] = sum_i D[b, t-w+1+i, i*512+kf]; relu(bias+max_t).
__global__ __launch_bounds__(256) void k_conv_epi(
    const unsigned short* __restrict__ D, const void* __restrict__ cb,
    float* __restrict__ con, int w, int widx, const int* __restrict__ dtf)
{
    const int f32m = *dtf;
    const int b  = blockIdx.y;
    const int kf = blockIdx.x * 256 + threadIdx.x;
    const int N  = w * 512;
    const unsigned short* Db = D + (long)b * T_SEQ * N;
    float mx = -1e30f;
    for (int t = 0; t < T_SEQ + w - 1; ++t) {
        float s = 0.f;
        for (int i = 0; i < w; ++i) {
            int tau = t - w + 1 + i;
            if (tau >= 0 && tau < T_SEQ) s += bf2f(Db[(long)tau * N + i * 512 + kf]);
        }
        mx = fmaxf(mx, s);
    }
    con[b * 2048 + widx * 512 + kf] = fmaxf(0.f, mx + ldsc(cb, kf, f32m));
}

// Assemble map input: [mean_gru(1024) | con(2048) | videos_origin(2048)].
__global__ __launch_bounds__(256) void k_gather(
    const float* __restrict__ mean, const float* __restrict__ con,
    const void* __restrict__ vo, float* __restrict__ fin, const int* __restrict__ dtf)
{
    const int f32m = *dtf;
    int e = blockIdx.x * 256 + threadIdx.x;     // < 655360
    int b = e / 5120, k = e - b * 5120;
    float v;
    if (k < 1024)      v = mean[b * 1024 + k];
    else if (k < 3072) v = con[b * 2048 + (k - 1024)];
    else               v = ldsc(vo, b * 2048 + (k - 3072), f32m);
    fin[e] = v;
}

// BN (eval) + row L2-normalize; output dtype follows the probed flag.
__global__ __launch_bounds__(256) void k_bn_norm(
    const float* __restrict__ feat, const void* __restrict__ gamma,
    const void* __restrict__ beta, void* __restrict__ out, const int* __restrict__ dtf)
{
    const int f32m = *dtf;
    const int b = blockIdx.x, tid = threadIdx.x;
    const float inv_c = 1.f / sqrtf(1.f + 1e-5f);
    float y[8]; float ss = 0.f;
    #pragma unroll
    for (int u = 0; u < 8; ++u) {
        int o = u * 256 + tid;
        float v = feat[b * 2048 + o] * inv_c * ldsc(gamma, o, f32m) + ldsc(beta, o, f32m);
        y[u] = v; ss += v * v;
    }
    #pragma unroll
    for (int off = 32; off >= 1; off >>= 1) ss += __shfl_down(ss, off, 64);
    __shared__ float rs[4];
    if ((tid & 63) == 0) rs[tid >> 6] = ss;
    __syncthreads();
    float rn = 1.f / sqrtf(rs[0] + rs[1] + rs[2] + rs[3]);
    #pragma unroll
    for (int u = 0; u < 8; ++u) {
        int o = u * 256 + tid;
        float v = y[u] * rn;
        if (f32m) ((float*)out)[b * 2048 + o] = v;
        else      ((unsigned short*)out)[b * 2048 + o] = f2bf(v);
    }
}

extern "C" void kernel_launch(void* const* d_in, const int* in_sizes, int n_in,
                              void* d_out, int out_size, void* d_ws, size_t ws_size,
                              hipStream_t stream)
{
    const void* videos  = d_in[0];
    const void* vorigin = d_in[1];
    const int*  lengths = (const int*)d_in[2];
    const void* mask    = d_in[3];
    const void* Wih_f = d_in[5];
    const void* Whh_f = d_in[6];
    const void* bih_f = d_in[7];
    const void* bhh_f = d_in[8];
    const void* Wih_b = d_in[9];
    const void* Whh_b = d_in[10];
    const void* bih_b = d_in[11];
    const void* bhh_b = d_in[12];
    // d_in[13..16] attention: dead (softmax over size-1 axis == 1)
    const void* cw[4] = { d_in[17], d_in[19], d_in[21], d_in[23] };
    const void* cb[4] = { d_in[18], d_in[20], d_in[22], d_in[24] };
    const void* map_W = d_in[25];
    const void* map_b = d_in[26];
    const void* gamma = d_in[27];
    const void* beta  = d_in[28];

    // --- workspace layout (bytes), total 98,578,436 B ---
    unsigned char* W = (unsigned char*)d_ws;
    unsigned short* pre  = (unsigned short*)W;               // 2*10240*1536 bf16 (conv D aliases)
    unsigned short* Mp   = (unsigned short*)(W + 62914560);  // 128*88*1024 bf16
    float* h0    = (float*)(W + 85983232);                   // 2*128*512 f32
    float* h1    = h0 + 131072;
    float* Wt    = (float*)(W + 87031808);                   // 2*3*512*512 f32
    float* bhh32 = (float*)(W + 93323264);                   // 3072 f32
    float* mean  = (float*)(W + 93335552);                   // 128*1024 f32
    float* con   = (float*)(W + 93859840);                   // 128*2048 f32
    float* fin   = (float*)(W + 94908416);                   // 128*5120 f32
    float* feat  = (float*)(W + 97529856);                   // 128*2048 f32
    int*   dtf   = (int*)(W + 98578432);                     // dtype flag

    k_probe<<<1, 64, 0, stream>>>((const unsigned short*)videos, dtf);

    hipMemsetAsync(Mp, 0, 23068672, stream);
    hipMemsetAsync(h0, 0, 1048576, stream);

    k_prep<<<6144, 256, 0, stream>>>(Whh_f, Whh_b, bhh_f, bhh_b, Wt, bhh32, dtf);

    // GRU input projection: pre[d][b*80+t][1536] = videos @ Wih_d^T + bih_d (bf16 out)
    gemm_mfma<1><<<dim3(24, 80), 256, 0, stream>>>(
        (const unsigned short*)videos, 0l, 10240, 0l, 2048,
        (const unsigned short*)Wih_f, (const unsigned short*)Wih_b, 1536, 1536, 2048l, 0l,
        (const unsigned short*)bih_f, (const unsigned short*)bih_b, 1,
        pre, 15728640l, 1536l, 2048, dtf);
    gemm_nt<2, 1><<<dim3(24, 80), 256, 0, stream>>>(          // f32 fallback (gated)
        videos, 0l, 10240, 0l, 2048,
        Wih_f, Wih_b, 1536, 1536, 2048l, 0l,
        bih_f, bih_b, 1,
        pre, 15728640l, 1536l, 2048, 2, dtf);

    for (int t = 0; t < T_SEQ; ++t) {
        float* hp = (t & 1) ? h1 : h0;
        float* hn = (t & 1) ? h0 : h1;
        k_gru_step<<<dim3(16, 8, 2), 256, 0, stream>>>(t, pre, Wt, bhh32, hp, hn, Mp);
    }

    k_mask_mean<<<dim3(4, 128), 256, 0, stream>>>(Mp, mask, lengths, mean, dtf);

    // Convs: D[(b,tau),(i*512+kf)] = sum_d Mp[b,tau,d]*cw[kf,i,d] (bf16 out into pre)
    for (int wi = 0; wi < 4; ++wi) {
        int ww = wi + 2;
        int N  = ww * 512;
        gemm_mfma<1><<<dim3(N / 128, 80), 256, 0, stream>>>(
            Mp, 4096l, 80, 90112l, 1024,
            (const unsigned short*)cw[wi], nullptr, 1 << 30, 512, (long)(ww * 1024), 1024l,
            nullptr, nullptr, 0,
            pre, 0l, (long)N, 1024, dtf);
        gemm_nt<1, 1><<<dim3(N / 128, 80), 256, 0, stream>>>( // f32-mode fallback (gated)
            Mp, 4096l, 80, 90112l, 1024,
            cw[wi], nullptr, 1 << 30, 512, (long)(ww * 1024), 1024l,
            nullptr, nullptr, 0,
            pre, 0l, (long)N, 1024, 2, dtf);
        k_conv_epi<<<dim3(2, 128), 256, 0, stream>>>(pre, cb[wi], con, ww, wi, dtf);
    }

    k_gather<<<2560, 256, 0, stream>>>(mean, con, vorigin, fin, dtf);

    // feat = fin @ map_W^T + map_b (f32 A; tiny -> legacy path, always runs)
    gemm_nt<0, 0><<<dim3(16, 1), 256, 0, stream>>>(
        fin, 0l, 128, 0l, 5120,
        map_W, nullptr, 1 << 30, 2048, 5120l, 0l,
        map_b, nullptr, 1,
        feat, 0l, 2048l, 5120, 0, dtf);

    k_bn_norm<<<128, 256, 0, stream>>>(feat, gamma, beta, d_out, dtf);
}

// Round 5
// 2448.067 us; speedup vs baseline: 3.5660x; 3.5660x over previous
//
#include <hip/hip_runtime.h>
#include <hip/hip_bf16.h>

// Video_multilevel_encoding — round 5: f32 inputs/output COMMITTED (rounds 2+3 passed only
// via the probed f32 path: probe set flag=1, f32 legacy ran, f32 output store validated).
// bf16 MFMA for the GEMM bulk with dual-mode staging:
//   bf16 ws tensors  -> global_load_lds width-16 (async direct-to-LDS)
//   f32 input tensors -> float4 x2 load, RNE cvt, ds_write_b128
// Carried algebra: attention softmax over size-1 axis == 1 -> H2 == gru (att weights dead);
// convs are NT-GEMMs over masked gru rows + shift-add/max epilogue; GRU h carried f32,
// bf16 only as MFMA input (round-2 f32 path already stored pre/Mp bf16 at absmax 4.9e-4).

#define T_SEQ 80

typedef __attribute__((ext_vector_type(8))) short short8;
typedef __attribute__((ext_vector_type(4))) float floatx4;

__device__ __forceinline__ float bf2f(unsigned short s) {
    union { unsigned int u; float f; } c; c.u = ((unsigned int)s) << 16; return c.f;
}
__device__ __forceinline__ unsigned short f2bf(float f) {
    union { float f; unsigned int u; } c; c.f = f;
    unsigned int u = c.u;
    u += 0x7fffu + ((u >> 16) & 1u);   // RNE
    return (unsigned short)(u >> 16);
}
// async global->LDS, 16B/lane; LDS dest wave-uniform base (HW scatters lane*16)
__device__ __forceinline__ void gld16(const unsigned short* g, unsigned short* lds_uniform) {
    __builtin_amdgcn_global_load_lds(
        (const __attribute__((address_space(1))) void*)g,
        (__attribute__((address_space(3))) void*)lds_uniform, 16, 0, 0);
}
// f32 source -> 8 bf16 into LDS (per-lane scatter via ds_write_b128)
__device__ __forceinline__ void stage8_f32(const float* __restrict__ src, unsigned short* __restrict__ dst) {
    float4 a = *(const float4*)src;
    float4 b = *(const float4*)(src + 4);
    short8 v;
    v[0] = (short)f2bf(a.x); v[1] = (short)f2bf(a.y); v[2] = (short)f2bf(a.z); v[3] = (short)f2bf(a.w);
    v[4] = (short)f2bf(b.x); v[5] = (short)f2bf(b.y); v[6] = (short)f2bf(b.z); v[7] = (short)f2bf(b.w);
    *(short8*)dst = v;
}

// ---------------------------------------------------------------------------
// MFMA bf16 NT-GEMM, dual-mode staging. C[m,n] = sum_k A[m,k]*B[n,k] (+bias[n]).
// AF32/BF32: source dtype of A/B (1 = f32 input tensor, 0 = bf16 ws tensor).
// A row offset = a_base + (m/a_rpb)*a_bstride + (m%a_rpb)*a_rstride (elements).
// B row r = n - d*n_split (d = n>=n_split): (r%b_mod)*b_sa + (r/b_mod)*b_sb.
// C idx = z*zout + (d?out_dsplit:0) + m*ldc + r.  K-range = [z*kchunk,(z+1)*kchunk).
// 128x128 tile, BK=32, 256 thr (4 waves x 4x4 16x16x32 tiles).
// Requires M%128==0, N%128==0 (n_split%128 if used), kchunk%32==0, rows 16B-aligned.
// ---------------------------------------------------------------------------
template<int AF32, int BF32, int OUTBF>
__global__ __launch_bounds__(256) void gemm_mfma(
    const void* __restrict__ Av, long a_base, int a_rpb, long a_bstride, int a_rstride,
    const void* __restrict__ B1v, const void* __restrict__ B2v,
    int n_split, int b_mod, long b_sa, long b_sb,
    const float* __restrict__ bias1, const float* __restrict__ bias2, int has_bias,
    void* __restrict__ Cout, long out_dsplit, long ldc,
    int kchunk, long zout)
{
    __shared__ __align__(16) unsigned short As[128 * 32];
    __shared__ __align__(16) unsigned short Bs[128 * 32];
    const int tid = threadIdx.x, wave = tid >> 6, lane = tid & 63;
    const int m0 = blockIdx.y * 128, n0 = blockIdx.x * 128;
    const long kbeg = (long)blockIdx.z * kchunk;

    // [128][32]-bf16 tile = 512 8-elem chunks; 2 chunks/thread. chunk c = 4r+p covers
    // row r cols [8p,8p+8); LDS elems [8c, 8c+8).
    const int c0 = wave * 64 + lane, c1 = 256 + c0;
    const int rA0 = c0 >> 2, pA0 = c0 & 3, rA1 = c1 >> 2, pA1 = c1 & 3;
    const int am0 = m0 + rA0, am1 = m0 + rA1;
    const long aoff0 = a_base + (long)(am0 / a_rpb) * a_bstride + (long)(am0 % a_rpb) * a_rstride + pA0 * 8 + kbeg;
    const long aoff1 = a_base + (long)(am1 / a_rpb) * a_bstride + (long)(am1 % a_rpb) * a_rstride + pA1 * 8 + kbeg;

    const int bn0 = n0 + rA0, bn1 = n0 + rA1;
    const int bd0 = (bn0 >= n_split), bd1 = (bn1 >= n_split);
    const int br0 = bn0 - (bd0 ? n_split : 0), br1 = bn1 - (bd1 ? n_split : 0);
    const long boff0 = (long)(br0 % b_mod) * b_sa + (long)(br0 / b_mod) * b_sb + pA0 * 8 + kbeg;
    const long boff1 = (long)(br1 % b_mod) * b_sa + (long)(br1 / b_mod) * b_sb + pA1 * 8 + kbeg;
    const void* Bp0 = bd0 ? B2v : B1v;
    const void* Bp1 = bd1 ? B2v : B1v;

    const int frow = lane & 15, fq = lane >> 4;
    const int wm = (wave >> 1) * 64, wn = (wave & 1) * 64;

    floatx4 acc[4][4];
    #pragma unroll
    for (int i = 0; i < 4; ++i)
        #pragma unroll
        for (int j = 0; j < 4; ++j) acc[i][j] = (floatx4)0.f;

    for (int k0 = 0; k0 < kchunk; k0 += 32) {
        if (AF32) {
            stage8_f32((const float*)Av + aoff0 + k0, As + c0 * 8);
            stage8_f32((const float*)Av + aoff1 + k0, As + c1 * 8);
        } else {
            gld16((const unsigned short*)Av + aoff0 + k0, As + (wave * 64) * 8);
            gld16((const unsigned short*)Av + aoff1 + k0, As + (256 + wave * 64) * 8);
        }
        if (BF32) {
            stage8_f32((const float*)Bp0 + boff0 + k0, Bs + c0 * 8);
            stage8_f32((const float*)Bp1 + boff1 + k0, Bs + c1 * 8);
        } else {
            gld16((const unsigned short*)Bp0 + boff0 + k0, Bs + (wave * 64) * 8);
            gld16((const unsigned short*)Bp1 + boff1 + k0, Bs + (256 + wave * 64) * 8);
        }
        __syncthreads();
        short8 af[4], bf[4];
        #pragma unroll
        for (int i = 0; i < 4; ++i) {
            af[i] = *(const short8*)&As[(wm + i * 16 + frow) * 32 + fq * 8];
            bf[i] = *(const short8*)&Bs[(wn + i * 16 + frow) * 32 + fq * 8];
        }
        #pragma unroll
        for (int mi = 0; mi < 4; ++mi)
            #pragma unroll
            for (int ni = 0; ni < 4; ++ni)
                acc[mi][ni] = __builtin_amdgcn_mfma_f32_16x16x32_bf16(af[mi], bf[ni], acc[mi][ni], 0, 0, 0);
        __syncthreads();
    }

    const long zoff = (long)blockIdx.z * zout;
    #pragma unroll
    for (int mi = 0; mi < 4; ++mi) {
        #pragma unroll
        for (int ni = 0; ni < 4; ++ni) {
            const int na = n0 + wn + ni * 16 + frow;     // C/D: col = lane&15
            const int dd = (na >= n_split);
            const int g  = na - (dd ? n_split : 0);
            float bv = has_bias ? (dd ? bias2 : bias1)[g] : 0.f;
            #pragma unroll
            for (int r = 0; r < 4; ++r) {                // row = (lane>>4)*4 + r
                const long gm = m0 + wm + mi * 16 + fq * 4 + r;
                const float v = acc[mi][ni][r] + bv;
                const long cidx = zoff + (dd ? out_dsplit : 0) + gm * ldc + g;
                if (OUTBF) ((unsigned short*)Cout)[cidx] = f2bf(v);
                else       ((float*)Cout)[cidx] = v;
            }
        }
    }
}

// Convert Whh (f32 [3H][512] x2 dirs) -> whh_bf bf16, row-layout unchanged.
__global__ __launch_bounds__(256) void k_whh_prep(
    const float* __restrict__ Whh_f, const float* __restrict__ Whh_b,
    unsigned short* __restrict__ whh_bf)
{
    int e = blockIdx.x * 256 + threadIdx.x;     // < 1572864
    int d = (e >= 786432);
    int rem = e - (d ? 786432 : 0);
    whh_bf[e] = f2bf((d ? Whh_b : Whh_f)[rem]);
}

// ---------------------------------------------------------------------------
// GRU recurrent step GEMM: gh[d][b=128][g=1536] = hbf[d][128][512] @ whh_bf_d^T.
// Pure bf16 (global_load_lds staging). Grid (12, 2=dir).
// ---------------------------------------------------------------------------
__global__ __launch_bounds__(256) void k_step_gemm(
    const unsigned short* __restrict__ hbf,
    const unsigned short* __restrict__ whh_bf,
    float* __restrict__ gh)
{
    __shared__ __align__(16) unsigned short As[128 * 32];
    __shared__ __align__(16) unsigned short Bs[128 * 32];
    const int tid = threadIdx.x, wave = tid >> 6, lane = tid & 63;
    const int d = blockIdx.y;
    const int n0 = blockIdx.x * 128;
    const unsigned short* Ab = hbf + d * 65536;
    const unsigned short* Bb = whh_bf + (long)d * 786432;

    const int c0 = wave * 64 + lane, c1 = 256 + c0;
    unsigned short* ldsA0 = As + (wave * 64) * 8;
    unsigned short* ldsA1 = As + (256 + wave * 64) * 8;
    unsigned short* ldsB0 = Bs + (wave * 64) * 8;
    unsigned short* ldsB1 = Bs + (256 + wave * 64) * 8;
    const int rA0 = c0 >> 2, pA0 = c0 & 3, rA1 = c1 >> 2, pA1 = c1 & 3;
    const unsigned short* gA0 = Ab + rA0 * 512 + pA0 * 8;
    const unsigned short* gA1 = Ab + rA1 * 512 + pA1 * 8;
    const unsigned short* gB0 = Bb + (long)(n0 + rA0) * 512 + pA0 * 8;
    const unsigned short* gB1 = Bb + (long)(n0 + rA1) * 512 + pA1 * 8;
    const int frow = lane & 15, fq = lane >> 4;
    const int wm = (wave >> 1) * 64, wn = (wave & 1) * 64;

    floatx4 acc[4][4];
    #pragma unroll
    for (int i = 0; i < 4; ++i)
        #pragma unroll
        for (int j = 0; j < 4; ++j) acc[i][j] = (floatx4)0.f;

    for (int k0 = 0; k0 < 512; k0 += 32) {
        gld16(gA0 + k0, ldsA0);
        gld16(gA1 + k0, ldsA1);
        gld16(gB0 + k0, ldsB0);
        gld16(gB1 + k0, ldsB1);
        __syncthreads();
        short8 af[4], bf[4];
        #pragma unroll
        for (int i = 0; i < 4; ++i) {
            af[i] = *(const short8*)&As[(wm + i * 16 + frow) * 32 + fq * 8];
            bf[i] = *(const short8*)&Bs[(wn + i * 16 + frow) * 32 + fq * 8];
        }
        #pragma unroll
        for (int mi = 0; mi < 4; ++mi)
            #pragma unroll
            for (int ni = 0; ni < 4; ++ni)
                acc[mi][ni] = __builtin_amdgcn_mfma_f32_16x16x32_bf16(af[mi], bf[ni], acc[mi][ni], 0, 0, 0);
        __syncthreads();
    }

    float* out = gh + (long)d * 196608;
    #pragma unroll
    for (int mi = 0; mi < 4; ++mi)
        #pragma unroll
        for (int ni = 0; ni < 4; ++ni)
            #pragma unroll
            for (int r = 0; r < 4; ++r)
                out[(long)(wm + mi * 16 + fq * 4 + r) * 1536 + (n0 + wn + ni * 16 + frow)] = acc[mi][ni][r];
}

// Gate update: h = (1-z)*n + z*h. h stays f32; hbf (next GEMM input) and Mp get bf16.
__global__ __launch_bounds__(256) void k_gru_gate(
    int t, const float* __restrict__ gh, const unsigned short* __restrict__ pre,
    const float* __restrict__ bhh_f, const float* __restrict__ bhh_b,
    float* __restrict__ h, unsigned short* __restrict__ hbf, unsigned short* __restrict__ Mp)
{
    int e = blockIdx.x * 256 + threadIdx.x;     // < 131072
    int d = e >> 16, rem = e & 65535, b = rem >> 9, j = rem & 511;
    const float* g3 = gh + (long)d * 196608 + b * 1536 + j;
    const float* bh = (d ? bhh_b : bhh_f) + j;
    int ti = d ? (T_SEQ - 1 - t) : t;
    const unsigned short* pb = pre + (long)d * 15728640 + ((long)(b * T_SEQ + ti)) * 1536 + j;
    float gr = g3[0]    + bh[0];
    float gz = g3[512]  + bh[512];
    float gn = g3[1024] + bh[1024];
    float r = 1.f / (1.f + expf(-(bf2f(pb[0]) + gr)));
    float z = 1.f / (1.f + expf(-(bf2f(pb[512]) + gz)));
    float n = tanhf(bf2f(pb[1024]) + r * gn);
    long hi = (long)d * 65536 + b * 512 + j;
    float hnew = (1.f - z) * n + z * h[hi];
    h[hi] = hnew;
    hbf[hi] = f2bf(hnew);
    Mp[(long)b * 90112 + (long)(4 + ti) * 1024 + d * 512 + j] = f2bf(hnew);
}

// Mask Mp in place (bf16 * {0,1} lossless) and mean over valid steps. mask is f32.
__global__ __launch_bounds__(256) void k_mask_mean(
    unsigned short* __restrict__ Mp, const float* __restrict__ mask,
    const int* __restrict__ lengths, float* __restrict__ mean)
{
    const int b = blockIdx.y;
    const int c = blockIdx.x * 256 + threadIdx.x;
    float acc = 0.f;
    unsigned short* base = Mp + (long)b * 90112 + 4096 + c;
    for (int t = 0; t < T_SEQ; ++t) {
        float m = mask[b * T_SEQ + t];
        float v = bf2f(base[t * 1024]) * m;
        base[t * 1024] = f2bf(v);
        acc += v;
    }
    mean[b * 1024 + c] = acc / (float)lengths[b];
}

// Conv epilogue over bf16 D: c[b,kf,t] = sum_i D[b, t-w+1+i, i*512+kf]; relu(bias+max_t).
__global__ __launch_bounds__(256) void k_conv_epi(
    const unsigned short* __restrict__ D, const float* __restrict__ cb,
    float* __restrict__ con, int w, int widx)
{
    const int b  = blockIdx.y;
    const int kf = blockIdx.x * 256 + threadIdx.x;
    const int N  = w * 512;
    const unsigned short* Db = D + (long)b * T_SEQ * N;
    float mx = -1e30f;
    for (int t = 0; t < T_SEQ + w - 1; ++t) {
        float s = 0.f;
        for (int i = 0; i < w; ++i) {
            int tau = t - w + 1 + i;
            if (tau >= 0 && tau < T_SEQ) s += bf2f(Db[(long)tau * N + i * 512 + kf]);
        }
        mx = fmaxf(mx, s);
    }
    con[b * 2048 + widx * 512 + kf] = fmaxf(0.f, mx + cb[kf]);
}

// Assemble map input (bf16 for MFMA map GEMM): [mean | con | videos_origin(f32)].
__global__ __launch_bounds__(256) void k_gather(
    const float* __restrict__ mean, const float* __restrict__ con,
    const float* __restrict__ vo, unsigned short* __restrict__ fin)
{
    int e = blockIdx.x * 256 + threadIdx.x;     // < 655360
    int b = e / 5120, k = e - b * 5120;
    float v;
    if (k < 1024)      v = mean[b * 1024 + k];
    else if (k < 3072) v = con[b * 2048 + (k - 1024)];
    else               v = vo[b * 2048 + (k - 3072)];
    fin[e] = f2bf(v);
}

// Reduce split-K partials + bias (f32) -> feat.
__global__ __launch_bounds__(256) void k_map_reduce(
    const float* __restrict__ part, const float* __restrict__ map_b,
    float* __restrict__ feat)
{
    int e = blockIdx.x * 256 + threadIdx.x;     // < 262144
    float s = map_b[e & 2047];
    #pragma unroll
    for (int z = 0; z < 8; ++z) s += part[(long)z * 262144 + e];
    feat[e] = s;
}

// BN (eval: /sqrt(1+eps)*gamma+beta) + row L2-normalize -> f32 out.
__global__ __launch_bounds__(256) void k_bn_norm(
    const float* __restrict__ feat, const float* __restrict__ gamma,
    const float* __restrict__ beta, float* __restrict__ out)
{
    const int b = blockIdx.x, tid = threadIdx.x;
    const float inv_c = 1.f / sqrtf(1.f + 1e-5f);
    float y[8]; float ss = 0.f;
    #pragma unroll
    for (int u = 0; u < 8; ++u) {
        int o = u * 256 + tid;
        float v = feat[b * 2048 + o] * inv_c * gamma[o] + beta[o];
        y[u] = v; ss += v * v;
    }
    #pragma unroll
    for (int off = 32; off >= 1; off >>= 1) ss += __shfl_down(ss, off, 64);
    __shared__ float rs[4];
    if ((tid & 63) == 0) rs[tid >> 6] = ss;
    __syncthreads();
    float rn = 1.f / sqrtf(rs[0] + rs[1] + rs[2] + rs[3]);
    #pragma unroll
    for (int u = 0; u < 8; ++u) {
        int o = u * 256 + tid;
        out[b * 2048 + o] = y[u] * rn;
    }
}

extern "C" void kernel_launch(void* const* d_in, const int* in_sizes, int n_in,
                              void* d_out, int out_size, void* d_ws, size_t ws_size,
                              hipStream_t stream)
{
    const float* videos  = (const float*)d_in[0];
    const float* vorigin = (const float*)d_in[1];
    const int*   lengths = (const int*)d_in[2];
    const float* mask    = (const float*)d_in[3];
    // d_in[4] gru_text_out: unused by the reference
    const float* Wih_f = (const float*)d_in[5];
    const float* Whh_f = (const float*)d_in[6];
    const float* bih_f = (const float*)d_in[7];
    const float* bhh_f = (const float*)d_in[8];
    const float* Wih_b = (const float*)d_in[9];
    const float* Whh_b = (const float*)d_in[10];
    const float* bih_b = (const float*)d_in[11];
    const float* bhh_b = (const float*)d_in[12];
    // d_in[13..16] attention: dead (softmax over size-1 axis == 1)
    const float* cw[4] = { (const float*)d_in[17], (const float*)d_in[19],
                           (const float*)d_in[21], (const float*)d_in[23] };
    const float* cb[4] = { (const float*)d_in[18], (const float*)d_in[20],
                           (const float*)d_in[22], (const float*)d_in[24] };
    const float* map_W = (const float*)d_in[25];
    const float* map_b = (const float*)d_in[26];
    const float* gamma = (const float*)d_in[27];
    const float* beta  = (const float*)d_in[28];

    // --- workspace layout (bytes), total 95,420,416 (< 98,578,436 proven in round 2) ---
    unsigned char* W = (unsigned char*)d_ws;
    unsigned short* pre    = (unsigned short*)W;               // [2][10240][1536] bf16 (conv D + map part alias)
    unsigned short* Mp     = (unsigned short*)(W + 62914560);  // [128][88][1024] bf16 (pad rows never read)
    float*          h      = (float*)(W + 85983232);           // [2][128][512] f32
    unsigned short* hbf    = (unsigned short*)(W + 86507520);  // [2][128][512] bf16
    float*          gh     = (float*)(W + 86769664);           // [2][128][1536] f32
    float*          mean   = (float*)(W + 88342528);           // [128][1024] f32
    float*          con    = (float*)(W + 88866816);           // [128][2048] f32
    unsigned short* fin    = (unsigned short*)(W + 89915392);  // [128][5120] bf16
    float*          feat   = (float*)(W + 91226112);           // [128][2048] f32
    unsigned short* whh_bf = (unsigned short*)(W + 92274688);  // [2][1536][512] bf16
    float*          part   = (float*)W;                        // [8][128][2048] f32, aliases pre (dead then)

    hipMemsetAsync(h, 0, 786432, stream);   // h + hbf contiguous -> one memset

    k_whh_prep<<<6144, 256, 0, stream>>>(Whh_f, Whh_b, whh_bf);

    // GRU input projection: pre[d][b*80+t][1536] = videos @ Wih_d^T + bih_d (bf16 out)
    gemm_mfma<1, 1, 1><<<dim3(24, 80, 1), 256, 0, stream>>>(
        videos, 0l, 10240, 0l, 2048,
        Wih_f, Wih_b, 1536, 1536, 2048l, 0l,
        bih_f, bih_b, 1,
        pre, 15728640l, 1536l, 2048, 0l);

    // Recurrent scan: per step, bf16 MFMA step-GEMM (both dirs) + fused gate update.
    for (int t = 0; t < T_SEQ; ++t) {
        k_step_gemm<<<dim3(12, 2), 256, 0, stream>>>(hbf, whh_bf, gh);
        k_gru_gate<<<512, 256, 0, stream>>>(t, gh, pre, bhh_f, bhh_b, h, hbf, Mp);
    }

    k_mask_mean<<<dim3(4, 128), 256, 0, stream>>>(Mp, mask, lengths, mean);

    // Convs: D[(b,tau),(i*512+kf)] = sum_d Mp[b,tau,d]*cw[kf,i,d] (bf16 D into pre region)
    for (int wi = 0; wi < 4; ++wi) {
        int ww = wi + 2;
        int N  = ww * 512;
        gemm_mfma<0, 1, 1><<<dim3(N / 128, 80, 1), 256, 0, stream>>>(
            Mp, 4096l, 80, 90112l, 1024,
            cw[wi], nullptr, 1 << 30, 512, (long)(ww * 1024), 1024l,
            nullptr, nullptr, 0,
            pre, 0l, (long)N, 1024, 0l);
        k_conv_epi<<<dim3(2, 128), 256, 0, stream>>>(pre, cb[wi], con, ww, wi);
    }

    k_gather<<<2560, 256, 0, stream>>>(mean, con, vorigin, fin);

    // map: split-K=8 MFMA GEMM -> f32 partials (alias pre), then reduce + bias.
    gemm_mfma<0, 1, 0><<<dim3(16, 1, 8), 256, 0, stream>>>(
        fin, 0l, 128, 0l, 5120,
        map_W, nullptr, 1 << 30, 2048, 5120l, 0l,
        nullptr, nullptr, 0,
        part, 0l, 2048l, 640, 262144l);
    k_map_reduce<<<1024, 256, 0, stream>>>(part, map_b, feat);

    k_bn_norm<<<128, 256, 0, stream>>>(feat, gamma, beta, (float*)d_out);
}